// Round 1
// 430.146 us; speedup vs baseline: 1.1029x; 1.1029x over previous
//
#include <hip/hip_runtime.h>

typedef short short8 __attribute__((ext_vector_type(8)));
typedef float f32x4 __attribute__((ext_vector_type(4)));

#define MFMA_BF16 __builtin_amdgcn_mfma_f32_16x16x32_bf16

__device__ __forceinline__ unsigned short f2bf(float f) {
  unsigned int u = __float_as_uint(f);
  u += 0x7fffu + ((u >> 16) & 1u);   // round-to-nearest-even
  return (unsigned short)(u >> 16);
}
__device__ __forceinline__ float bf2f(unsigned short u) {
  return __uint_as_float(((unsigned int)u) << 16);
}

// async global->LDS, 16B per lane. LDS dest = wave-uniform base + lane*16.
typedef __attribute__((address_space(1))) const unsigned int as1_u32;
typedef __attribute__((address_space(3))) unsigned int as3_u32;
__device__ __forceinline__ void gld16(const void* g, void* l) {
  __builtin_amdgcn_global_load_lds((as1_u32*)(unsigned long long)g,
                                   (as3_u32*)(unsigned int)(unsigned long long)l,
                                   16, 0, 0);
}

#define VMCNT(n) asm volatile("s_waitcnt vmcnt(" #n ")" ::: "memory")
__device__ __forceinline__ void barrier_raw() {
  asm volatile("" ::: "memory");
  __builtin_amdgcn_s_barrier();
  asm volatile("" ::: "memory");
}

// ---------------------------------------------------------------------------
// Fused f32 -> bf16 convert: 7 segments selected by blockIdx.y.
// ---------------------------------------------------------------------------
struct CvtArgs {
  const float* s[7];
  unsigned short* d[7];
  int n8[7];
};

__global__ __launch_bounds__(256) void cvtall(CvtArgs a) {
  const int seg = blockIdx.y;
  int i = blockIdx.x * 256 + threadIdx.x;
  if (i >= a.n8[seg]) return;
  const float4* s4 = (const float4*)a.s[seg];
  float4 x = s4[2 * i], y = s4[2 * i + 1];
  short8 o = {(short)f2bf(x.x), (short)f2bf(x.y), (short)f2bf(x.z), (short)f2bf(x.w),
              (short)f2bf(y.x), (short)f2bf(y.y), (short)f2bf(y.z), (short)f2bf(y.w)};
  *(short8*)&a.d[seg][(size_t)i * 8] = o;
}

// ---------------------------------------------------------------------------
// GEMM: C[m,n] = sum_k A[m,k]*W[n,k] + bias[n].  A (M,K) bf16, W (N,K) bf16.
// Phase-pipelined: BM=256 BN=128 BK=32, 512 thr (8 waves, 4Mx2N, wave 64x64).
// 4-slot LDS ring (96KB): compute tile t from slot t&3 while staging tile t+3
// (via global_load_lds w=16) into slot (t+3)&3 = slot last read at t-1 (WAR
// ordered by the end-of-tile barrier). Counted s_waitcnt vmcnt(6) once per
// tile (3 loads/thread/tile, 2 tiles in flight) - never drains to 0 in the
// main loop. LDS XOR-swizzle k^=((r>>1)&3)<<3 on BOTH sides (pre-swizzled
// global source + swizzled ds_read addr) -> conflict-free ds_read_b128.
// s_setprio(1) around the 16-MFMA cluster.
// Grid: NZ*256 blocks (16 m-tiles x 16 n-tiles); xcd=blk&7 owns 2 m-bands,
// walks n-major so W n-tile is L2-reused by both m-bands. M=4096 N=K=2048.
// ---------------------------------------------------------------------------
struct GemmArgs {
  const unsigned short* A[3];
  const unsigned short* W[3];
  const float* bias[3];
  unsigned short* Cb[3];
  float* Cf;
};

template <bool OUTBF, int NZ>
__global__ __launch_bounds__(512, 2) void gemm_bf16(GemmArgs g) {
  extern __shared__ unsigned short Sh[];  // 4 rings x ((256+128)*32) bf16
  const int B = blockIdx.x;
  const int z = B >> 8;                   // 256 tiles per z
  const int i = B & 255;
  const int xcd = i & 7;
  const int q = i >> 3;                   // 0..31
  const int bn = (q >> 1) * 128;
  const int bm = (xcd * 2 + (q & 1)) * 256;
  const int K = 2048, N = 2048, NT = 64;
  const int RS = 12288;                   // ring stride (elements)

  const unsigned short* __restrict__ A = g.A[z];
  const unsigned short* __restrict__ W = g.W[z];
  const float* __restrict__ bias = g.bias[z];
  unsigned short* __restrict__ Cb = g.Cb[z];

  const int t = threadIdx.x, lane = t & 63, w = t >> 6;
  const int wr = w >> 1, wc = w & 1;
  const int quad = lane >> 4, l16 = lane & 15;

  // staging: per tile, 3 gld16/thread (A: 2 issues of 16 rows/wave, B: 1).
  // LDS dest is linear; source column carries the inverse swizzle so the
  // LDS content ends up swizzled.
  const int sk = ((lane & 3) * 8) ^ (((lane >> 3) & 3) << 3);
  const int srow = lane >> 2;             // 0..15
  const size_t gA0 = (size_t)(bm + w * 32 + srow) * K + sk;
  const size_t gA1 = (size_t)(bm + w * 32 + 16 + srow) * K + sk;
  const size_t gB  = (size_t)(bn + w * 16 + srow) * K + sk;
  const int lA0 = (w * 32) * 32;
  const int lA1 = (w * 32 + 16) * 32;
  const int lB  = 8192 + (w * 16) * 32;

#define STAGE(tt, ring)                                   \
  do {                                                    \
    const int kq = (tt) * 32;                             \
    unsigned short* Ld = &Sh[(ring) * RS];                \
    gld16(A + gA0 + kq, Ld + lA0);                        \
    gld16(A + gA1 + kq, Ld + lA1);                        \
    gld16(W + gB + kq, Ld + lB);                          \
  } while (0)

  // compute-side swizzled read offsets (swz bits come only from l16 since
  // fragment row base is a multiple of 16)
  const int ka = (quad * 8) ^ (((l16 >> 1) & 3) << 3);
  const int raA = (wr * 64 + l16) * 32 + ka;              // + mt*512
  const int raB = 8192 + (wc * 64 + l16) * 32 + ka;       // + nt*512

  const f32x4 fz = {0.f, 0.f, 0.f, 0.f};
  f32x4 acc[4][4];
  for (int a = 0; a < 4; ++a)
    for (int b = 0; b < 4; ++b) acc[a][b] = fz;

  // prologue: stage tiles 0,1,2 into rings 0,1,2; wait tile 0 (oldest 3)
  STAGE(0, 0);
  STAGE(1, 1);
  STAGE(2, 2);
  VMCNT(6);
  barrier_raw();

#pragma unroll 4
  for (int tt = 0; tt < NT; ++tt) {
    const unsigned short* Sr = &Sh[(tt & 3) * RS];
    short8 af[4], bv[4];
    for (int mt = 0; mt < 4; ++mt)
      af[mt] = *(const short8*)&Sr[raA + mt * 512];
    for (int nt = 0; nt < 4; ++nt)
      bv[nt] = *(const short8*)&Sr[raB + nt * 512];
    if (tt + 3 < NT) STAGE(tt + 3, (tt + 3) & 3);
    barrier_raw();
    __builtin_amdgcn_s_setprio(1);
    for (int mt = 0; mt < 4; ++mt)
      for (int nt = 0; nt < 4; ++nt)
        acc[mt][nt] = MFMA_BF16(af[mt], bv[nt], acc[mt][nt], 0, 0, 0);
    __builtin_amdgcn_s_setprio(0);
    if (tt < NT - 3) VMCNT(6);        // tile tt+1 landed; 2 tiles in flight
    else if (tt == NT - 3) VMCNT(3);  // epilogue drain
    else if (tt == NT - 2) VMCNT(0);
    barrier_raw();
  }
#undef STAGE

  for (int mt = 0; mt < 4; ++mt)
    for (int nt = 0; nt < 4; ++nt) {
      int row = bm + wr * 64 + mt * 16 + quad * 4;
      int col = bn + wc * 64 + nt * 16 + l16;
      float bc = bias[col];
      for (int r2 = 0; r2 < 4; ++r2) {
        float v = acc[mt][nt][r2] + bc;
        if (OUTBF) Cb[(size_t)(row + r2) * N + col] = f2bf(v);
        else       g.Cf[(size_t)(row + r2) * N + col] = v;
      }
    }
}

// ---------------------------------------------------------------------------
// Fused RMSNorm+rotary (Q,K) and V transpose.
// Blocks [0,16384): rmsrope, one wave per (b,h,l) row.
// Blocks [16384,17408): vtrans, Vf bf16 (b,l,e) -> Vt bf16 (b,h,d,l).
// ---------------------------------------------------------------------------
__global__ __launch_bounds__(256) void rmsvt(
    const unsigned short* __restrict__ Qf, const unsigned short* __restrict__ Kf,
    const unsigned short* __restrict__ Vf,
    const float* __restrict__ cosT, const float* __restrict__ sinT,
    unsigned short* __restrict__ Qb, unsigned short* __restrict__ Kb,
    unsigned short* __restrict__ Vt) {
  __shared__ unsigned short Vsh[64 * 136];
  if (blockIdx.x < 16384) {
    const int rid = blockIdx.x * 4 + (threadIdx.x >> 6);
    const int lane = threadIdx.x & 63;
    const int li = rid & 1023;
    const int bh = rid >> 10;
    const int hi = bh & 15, bi = bh >> 4;
    const int src = (bi * 1024 + li) * 2048 + hi * 128;
    const int dst = rid * 128;
    const float c = cosT[li * 64 + lane];
    const float s = sinT[li * 64 + lane];

    float q1 = bf2f(Qf[src + lane]), q2 = bf2f(Qf[src + 64 + lane]);
    float ss = q1 * q1 + q2 * q2;
    for (int off = 32; off; off >>= 1) ss += __shfl_xor(ss, off, 64);
    float r = rsqrtf(ss * (1.f / 128.f) + 1e-6f);
    float qa = q1 * r, qb2 = q2 * r;
    const float qsc = 0.08838834764831845f * 1.4426950408889634f;
    Qb[dst + lane]      = f2bf((qa * c - qb2 * s) * qsc);
    Qb[dst + 64 + lane] = f2bf((qa * s + qb2 * c) * qsc);

    float k1 = bf2f(Kf[src + lane]), k2 = bf2f(Kf[src + 64 + lane]);
    float ks = k1 * k1 + k2 * k2;
    for (int off = 32; off; off >>= 1) ks += __shfl_xor(ks, off, 64);
    float rk = rsqrtf(ks * (1.f / 128.f) + 1e-6f);
    float ka = k1 * rk, kb2 = k2 * rk;
    Kb[dst + lane]      = f2bf(ka * c - kb2 * s);
    Kb[dst + 64 + lane] = f2bf(ka * s + kb2 * c);
  } else {
    const int bid = blockIdx.x - 16384;
    const int t = threadIdx.x;
    const int bh = bid >> 4, l0 = (bid & 15) * 64;
    const int hi = bh & 15, bi = bh >> 4;
    {
      int row = t >> 2, c4 = t & 3;
      const unsigned short* src = &Vf[(size_t)(bi * 1024 + l0 + row) * 2048 + hi * 128];
      for (int i = 0; i < 4; ++i) {
        int chunk = c4 * 4 + i;
        *(int4*)&Vsh[row * 136 + chunk * 8] = *(const int4*)&src[chunk * 8];
      }
    }
    __syncthreads();
    {
      int d = t >> 1, half = t & 1;
      unsigned short* dst = &Vt[(size_t)bh * 131072 + (size_t)d * 1024 + l0 + half * 32];
      for (int g = 0; g < 4; ++g) {
        short8 o;
        for (int j = 0; j < 8; ++j)
          o[j] = (short)Vsh[(half * 32 + g * 8 + j) * 136 + d];
        *(short8*)&dst[g * 8] = o;
      }
    }
  }
}

// ---------------------------------------------------------------------------
// Flash attention, causal, static softmax max, s-SPLIT + balanced pairing.
// ---------------------------------------------------------------------------
__global__ __launch_bounds__(512, 4) void attn(
    const unsigned short* __restrict__ Qb, const unsigned short* __restrict__ Kb,
    const unsigned short* __restrict__ Vt, unsigned short* __restrict__ Of0,
    unsigned short* __restrict__ Of1, float* __restrict__ Lb) {
  __shared__ unsigned short Kl[64 * 136];
  __shared__ unsigned short Vl[128 * 72];
  __shared__ unsigned short Pl[8][16 * 72];
  const int t = threadIdx.x, lane = t & 63, w = t >> 6;
  const int quad = lane >> 4, l16 = lane & 15;
  const int B = blockIdx.x;
  const int bh = (B & 7) + 8 * ((B >> 3) & 7);
  const int jj = B >> 6;
  const int pair = jj >> 1, split = jj & 1;
  const unsigned short* Qh = Qb + (size_t)bh * 131072;
  const unsigned short* Kh = Kb + (size_t)bh * 131072;
  const unsigned short* Vh = Vt + (size_t)bh * 131072;
  unsigned short* Oh = (split ? Of1 : Of0) + (size_t)bh * 131072;
  float* Lh = Lb + split * 65536 + bh * 1024;

  const int krow = t >> 4, kcol = (t & 15) * 8;
  const int vdr = t >> 3, vc = (t & 7) * 8;
  const f32x4 fz = {0.f, 0.f, 0.f, 0.f};

  for (int ti = 0; ti < 2; ++ti) {
    const int qt = ti == 0 ? 7 - pair : pair;
    const int q0 = qt * 128;

    short8 aQ[4];
    {
      int qr = q0 + w * 16 + l16;
      for (int kk = 0; kk < 4; ++kk)
        aQ[kk] = *(const short8*)&Qh[(size_t)qr * 128 + kk * 32 + quad * 8];
    }
    f32x4 oacc[8];
    for (int i = 0; i < 8; ++i) oacc[i] = fz;
    float Lr[4] = {0.f, 0.f, 0.f, 0.f};
    const int nST = 2 * qt + 2;

    for (int st = split; st < nST; st += 2) {
      const int s0 = st * 64;
      __syncthreads();
      {
        *(int4*)&Kl[krow * 136 + kcol] =
            *(const int4*)&Kh[(size_t)(s0 + krow) * 128 + kcol];
        *(int4*)&Kl[(krow + 32) * 136 + kcol] =
            *(const int4*)&Kh[(size_t)(s0 + krow + 32) * 128 + kcol];
        *(int4*)&Vl[vdr * 72 + vc] =
            *(const int4*)&Vh[(size_t)vdr * 1024 + s0 + vc];
        *(int4*)&Vl[(vdr + 64) * 72 + vc] =
            *(const int4*)&Vh[(size_t)(vdr + 64) * 1024 + s0 + vc];
      }
      __syncthreads();

      f32x4 sfr[4];
      for (int j = 0; j < 4; ++j) sfr[j] = fz;
      for (int kk = 0; kk < 4; ++kk)
        for (int ni = 0; ni < 4; ++ni) {
          short8 bK = *(const short8*)&Kl[(ni * 16 + l16) * 136 + kk * 32 + quad * 8];
          sfr[ni] = MFMA_BF16(aQ[kk], bK, sfr[ni], 0, 0, 0);
        }

      const bool diag = (s0 + 63 > q0);
      for (int r = 0; r < 4; ++r) {
        int q = q0 + w * 16 + quad * 4 + r;
        float ps = 0.f;
        for (int ni = 0; ni < 4; ++ni) {
          float sv = sfr[ni][r];
          if (diag && (s0 + ni * 16 + l16 > q)) sv = -30000.f;
          float pp = exp2f(sv - 16.5f);
          ps += pp;
          Pl[w][(quad * 4 + r) * 72 + ni * 16 + l16] = f2bf(pp);
        }
        ps += __shfl_xor(ps, 1, 64);
        ps += __shfl_xor(ps, 2, 64);
        ps += __shfl_xor(ps, 4, 64);
        ps += __shfl_xor(ps, 8, 64);
        Lr[r] += ps;
      }

      for (int kk = 0; kk < 2; ++kk) {
        short8 aP = *(const short8*)&Pl[w][l16 * 72 + kk * 32 + quad * 8];
        for (int nt = 0; nt < 8; ++nt) {
          short8 bV = *(const short8*)&Vl[(nt * 16 + l16) * 72 + kk * 32 + quad * 8];
          oacc[nt] = MFMA_BF16(aP, bV, oacc[nt], 0, 0, 0);
        }
      }
    }

    for (int r = 0; r < 4; ++r) {
      int q = q0 + w * 16 + quad * 4 + r;
      size_t base = (size_t)q * 128;
      for (int nt = 0; nt < 8; ++nt)
        Oh[base + nt * 16 + l16] = f2bf(oacc[nt][r]);
      if (l16 == 0) Lh[q] = Lr[r];
    }
  }
}

// ---------------------------------------------------------------------------
// Combine split partials + v-projection removal. Out bf16 (b,l,e).
// ---------------------------------------------------------------------------
__global__ __launch_bounds__(256) void vnfix(
    const unsigned short* __restrict__ Of0, const unsigned short* __restrict__ Of1,
    const float* __restrict__ Lb, const unsigned short* __restrict__ Vf,
    unsigned short* __restrict__ Op) {
  const int rid = blockIdx.x * 4 + (threadIdx.x >> 6);
  const int lane = threadIdx.x & 63;
  const int li = rid & 1023;
  const int bh = rid >> 10;
  const int hi = bh & 15, bi = bh >> 4;
  const int src = (bi * 1024 + li) * 2048 + hi * 128;
  float inv = 1.f / (Lb[rid] + Lb[65536 + rid]);
  float o1 = (bf2f(Of0[(size_t)rid * 128 + lane]) + bf2f(Of1[(size_t)rid * 128 + lane])) * inv;
  float o2 = (bf2f(Of0[(size_t)rid * 128 + 64 + lane]) + bf2f(Of1[(size_t)rid * 128 + 64 + lane])) * inv;
  float v1 = bf2f(Vf[src + lane]), v2 = bf2f(Vf[src + 64 + lane]);
  float vv = v1 * v1 + v2 * v2;
  float dd = o1 * v1 + o2 * v2;
  for (int off = 32; off; off >>= 1) {
    vv += __shfl_xor(vv, off, 64);
    dd += __shfl_xor(dd, off, 64);
  }
  float vn = fmaxf(sqrtf(vv), 1e-9f);
  float tc = dd / (vn * vn);
  Op[src + lane]      = f2bf(o1 - tc * v1);
  Op[src + 64 + lane] = f2bf(o2 - tc * v2);
}

// ---------------------------------------------------------------------------
// Workspace map (128 MB), b=4,l=1024,e=2048,h=16,d=128:
//  0-16M   Xq bf16          -> Qb (b,h,l,d) after rmsvt
//  16-32M  Xk bf16          -> Kb
//  32-48M  Xv bf16          -> Vt (b,h,d,l) after rmsvt
//  48-56M  Wqb | 56-64M Wkb -> Opb bf16 (b,l,e) 48-64M after vnfix
//  64-72M  Wvb              -> Lb f32 (512K) by attn
//  72-80M  Wob (live to end)
//  80-96M  Qf bf16          -> Of0 bf16 partial
//  96-112M Kf bf16          -> Of1 bf16 partial
//  112-128M Vf bf16 (live until vnfix)
// ---------------------------------------------------------------------------
extern "C" void kernel_launch(void* const* d_in, const int* in_sizes, int n_in,
                              void* d_out, int out_size, void* d_ws, size_t ws_size,
                              hipStream_t stream) {
  const float* query = (const float*)d_in[0];
  const float* key   = (const float*)d_in[1];
  const float* value = (const float*)d_in[2];
  const float* cosT  = (const float*)d_in[4];
  const float* sinT  = (const float*)d_in[5];
  const float* Wq = (const float*)d_in[6];
  const float* bq = (const float*)d_in[7];
  const float* Wk = (const float*)d_in[8];
  const float* bk = (const float*)d_in[9];
  const float* Wv = (const float*)d_in[10];
  const float* bv = (const float*)d_in[11];
  const float* Wo = (const float*)d_in[12];
  const float* bo = (const float*)d_in[13];
  float* out = (float*)d_out;

  char* ws = (char*)d_ws;
  const size_t MB = 1048576;
  unsigned short* Xq  = (unsigned short*)(ws);
  unsigned short* Xk  = (unsigned short*)(ws + 16 * MB);
  unsigned short* Xv  = (unsigned short*)(ws + 32 * MB);
  unsigned short* Wqb = (unsigned short*)(ws + 48 * MB);
  unsigned short* Wkb = (unsigned short*)(ws + 56 * MB);
  unsigned short* Wvb = (unsigned short*)(ws + 64 * MB);
  unsigned short* Wob = (unsigned short*)(ws + 72 * MB);
  unsigned short* Qf  = (unsigned short*)(ws + 80 * MB);
  unsigned short* Kf  = (unsigned short*)(ws + 96 * MB);
  unsigned short* Vf  = (unsigned short*)(ws + 112 * MB);
  unsigned short* Qbb = Xq;
  unsigned short* Kbb = Xk;
  unsigned short* Vtb = Xv;
  unsigned short* Of0 = Qf;
  unsigned short* Of1 = Kf;
  float*          Lbp = (float*)(ws + 64 * MB);
  unsigned short* Opb = (unsigned short*)(ws + 48 * MB);

  // 1. converts
  CvtArgs ca;
  ca.s[0] = query; ca.d[0] = Xq;  ca.n8[0] = 1048576;
  ca.s[1] = key;   ca.d[1] = Xk;  ca.n8[1] = 1048576;
  ca.s[2] = value; ca.d[2] = Xv;  ca.n8[2] = 1048576;
  ca.s[3] = Wq;    ca.d[3] = Wqb; ca.n8[3] = 524288;
  ca.s[4] = Wk;    ca.d[4] = Wkb; ca.n8[4] = 524288;
  ca.s[5] = Wv;    ca.d[5] = Wvb; ca.n8[5] = 524288;
  ca.s[6] = Wo;    ca.d[6] = Wob; ca.n8[6] = 524288;
  cvtall<<<dim3(4096, 7), 256, 0, stream>>>(ca);

  // 2. Q,K,V projections (one dispatch, pipelined ring-4 GEMM)
  GemmArgs gp;
  gp.A[0] = Xq;  gp.A[1] = Xk;  gp.A[2] = Xv;
  gp.W[0] = Wqb; gp.W[1] = Wkb; gp.W[2] = Wvb;
  gp.bias[0] = bq; gp.bias[1] = bk; gp.bias[2] = bv;
  gp.Cb[0] = Qf; gp.Cb[1] = Kf; gp.Cb[2] = Vf;
  gp.Cf = nullptr;
  gemm_bf16<true, 3><<<768, 512, 98304, stream>>>(gp);

  // 3. rmsnorm+rope + V transpose (one dispatch)
  rmsvt<<<17408, 256, 0, stream>>>(Qf, Kf, Vf, cosT, sinT, Qbb, Kbb, Vtb);

  // 4. attention
  attn<<<512, 512, 0, stream>>>(Qbb, Kbb, Vtb, Of0, Of1, Lbp);

  // 5. combine + v-projection removal
  vnfix<<<16384, 256, 0, stream>>>(Of0, Of1, Lbp, Vf, Opb);

  // 6. output projection
  GemmArgs go;
  go.A[0] = Opb; go.A[1] = nullptr; go.A[2] = nullptr;
  go.W[0] = Wob; go.W[1] = nullptr; go.W[2] = nullptr;
  go.bias[0] = bo; go.bias[1] = nullptr; go.bias[2] = nullptr;
  go.Cb[0] = nullptr; go.Cb[1] = nullptr; go.Cb[2] = nullptr;
  go.Cf = out;
  gemm_bf16<false, 1><<<256, 512, 98304, stream>>>(go);
}